// Round 2
// baseline (279.106 us; speedup 1.0000x reference)
//
#include <hip/hip_runtime.h>
#include <stdint.h>

typedef __bf16 bf16_t;
typedef bf16_t bf16x8 __attribute__((ext_vector_type(8)));
typedef bf16_t bf16x4 __attribute__((ext_vector_type(4)));
typedef float f32x4 __attribute__((ext_vector_type(4)));

#define DEV __device__ __forceinline__

DEV void gload_lds16(const void* g, void* l) {
  __builtin_amdgcn_global_load_lds(
      (__attribute__((address_space(1))) void*)(g),
      (__attribute__((address_space(3))) void*)(l), 16, 0, 0);
}

// ---------------- convert kernels ----------------
__global__ __launch_bounds__(256) void cvt2_kernel(
    const float* __restrict__ x, const float* __restrict__ q,
    bf16_t* __restrict__ xb, bf16_t* __restrict__ qb) {
  const float* s = blockIdx.y ? q : x;
  bf16_t* d = blockIdx.y ? qb : xb;
  int i = blockIdx.x * 256 + threadIdx.x;
  if (i < 524288) {
    const float4* sp = (const float4*)s + (size_t)i * 2;
    float4 a = sp[0], b = sp[1];
    bf16x8 o;
    o[0] = (bf16_t)a.x; o[1] = (bf16_t)a.y; o[2] = (bf16_t)a.z; o[3] = (bf16_t)a.w;
    o[4] = (bf16_t)b.x; o[5] = (bf16_t)b.y; o[6] = (bf16_t)b.z; o[7] = (bf16_t)b.w;
    *(bf16x8*)(d + (size_t)i * 8) = o;
  }
}

__global__ __launch_bounds__(256) void cvtw_kernel(
    const float* __restrict__ Wq, const float* __restrict__ Wk,
    const float* __restrict__ Wv, const float* __restrict__ Wo,
    bf16_t* __restrict__ dst) {
  int y = blockIdx.y;
  const float* s = (y == 0) ? Wq : (y == 1) ? Wk : (y == 2) ? Wv : Wo;
  bf16_t* d = dst + (size_t)y * 262144;
  int i = blockIdx.x * 256 + threadIdx.x;
  if (i < 32768) {
    const float4* sp = (const float4*)s + (size_t)i * 2;
    float4 a = sp[0], b = sp[1];
    bf16x8 o;
    o[0] = (bf16_t)a.x; o[1] = (bf16_t)a.y; o[2] = (bf16_t)a.z; o[3] = (bf16_t)a.w;
    o[4] = (bf16_t)b.x; o[5] = (bf16_t)b.y; o[6] = (bf16_t)b.z; o[7] = (bf16_t)b.w;
    *(bf16x8*)(d + (size_t)i * 8) = o;
  }
}

// ---------------- GEMM core: C[128x128] = A[128xK] * W[128xK]^T ----------------
DEV void gemm_core(const bf16_t* __restrict__ A, const bf16_t* __restrict__ W,
                   char* smem, f32x4 (&acc)[4][4]) {
  const int tid = threadIdx.x;
  const int lane = tid & 63;
  const int wid = tid >> 6;
  const int wr = wid >> 1, wc = wid & 1;
  const int bx = blockIdx.x, by = blockIdx.y;

  uint32_t goffA[4], goffB[4], ldsoff[4];
#pragma unroll
  for (int c = 0; c < 4; ++c) {
    uint32_t o = (uint32_t)wid * 4096u + (uint32_t)c * 1024u + (uint32_t)lane * 16u;
    uint32_t row = o >> 7;
    uint32_t inner = (o & 127u) ^ ((row & 7u) << 4);
    goffA[c] = ((uint32_t)by * 128u + row) * 1024u + inner;
    goffB[c] = ((uint32_t)bx * 128u + row) * 1024u + inner;
    ldsoff[c] = o - (uint32_t)lane * 16u;
  }
  uint32_t offA[4][2], offB[4][2];
#pragma unroll
  for (int i = 0; i < 4; ++i)
#pragma unroll
    for (int kk = 0; kk < 2; ++kk) {
      uint32_t ra = (uint32_t)(wr * 64 + i * 16 + (lane & 15));
      offA[i][kk] = ra * 128u + (((uint32_t)kk * 64u + ((lane >> 4) * 16u)) ^ ((ra & 7u) << 4));
      uint32_t rb = (uint32_t)(wc * 64 + i * 16 + (lane & 15));
      offB[i][kk] = rb * 128u + (((uint32_t)kk * 64u + ((lane >> 4) * 16u)) ^ ((rb & 7u) << 4));
    }

  const char* Ab = (const char*)A;
  const char* Wb = (const char*)W;

#pragma unroll
  for (int c = 0; c < 4; ++c) {
    gload_lds16(Ab + goffA[c], smem + ldsoff[c]);
    gload_lds16(Wb + goffB[c], smem + 16384 + ldsoff[c]);
  }
  asm volatile("s_waitcnt vmcnt(0)" ::: "memory");
  __syncthreads();

#pragma unroll 1
  for (int kt = 0; kt < 8; ++kt) {
    const int buf = kt & 1;
    char* cur = smem + buf * 32768;
    if (kt < 7) {
      char* nxt = smem + (buf ^ 1) * 32768;
      uint32_t gk = (uint32_t)(kt + 1) * 128u;
#pragma unroll
      for (int c = 0; c < 4; ++c) {
        gload_lds16(Ab + goffA[c] + gk, nxt + ldsoff[c]);
        gload_lds16(Wb + goffB[c] + gk, nxt + 16384 + ldsoff[c]);
      }
    }
    bf16x8 af[4][2], bfr[4][2];
#pragma unroll
    for (int kk = 0; kk < 2; ++kk)
#pragma unroll
      for (int i = 0; i < 4; ++i) {
        af[i][kk] = *(const bf16x8*)(cur + offA[i][kk]);
        bfr[i][kk] = *(const bf16x8*)(cur + 16384 + offB[i][kk]);
      }
#pragma unroll
    for (int kk = 0; kk < 2; ++kk)
#pragma unroll
      for (int mi = 0; mi < 4; ++mi)
#pragma unroll
        for (int nj = 0; nj < 4; ++nj)
          acc[mi][nj] = __builtin_amdgcn_mfma_f32_16x16x32_bf16(
              af[mi][kk], bfr[nj][kk], acc[mi][nj], 0, 0, 0);
    asm volatile("s_waitcnt vmcnt(0)" ::: "memory");
    __syncthreads();
  }
}

// QKV projection. z=0 -> Q (pre-scaled by 0.125*log2e), z=1 -> K, z=2 -> V^T.
// Q,K layout [B*H][S][64]; V stored transposed [B*H][64][S].
__global__ __launch_bounds__(256) void gemm_qkv_kernel(
    const bf16_t* __restrict__ xb, const bf16_t* __restrict__ qb,
    const bf16_t* __restrict__ Wb, const float* __restrict__ bq,
    const float* __restrict__ bk, const float* __restrict__ bv,
    bf16_t* __restrict__ Qh, bf16_t* __restrict__ Kh, bf16_t* __restrict__ VT) {
  __shared__ char smem[65536];
  const int z = blockIdx.z;
  const bf16_t* A = (z == 0) ? qb : xb;
  const bf16_t* W = Wb + (size_t)z * 262144;
  const float* bias = (z == 0) ? bq : (z == 1) ? bk : bv;

  f32x4 acc[4][4] = {};
  gemm_core(A, W, smem, acc);

  const int lane = threadIdx.x & 63, wid = threadIdx.x >> 6;
  const int wr = wid >> 1, wc = wid & 1;
  const int colbase = blockIdx.x * 128 + wc * 64 + (lane & 15);
  const int rowbase = blockIdx.y * 128 + wr * 64 + ((lane >> 4) << 2);

  if (z == 2) {
    // V^T: VT[(bh*64 + d)*2048 + s], rr index is s-contiguous -> 8B stores
#pragma unroll
    for (int nj = 0; nj < 4; ++nj) {
      int c = colbase + nj * 16;
      float bb = bias[c];
      int h = c >> 6, d = c & 63;
#pragma unroll
      for (int mi = 0; mi < 4; ++mi) {
        int r0 = rowbase + mi * 16;
        int b = r0 >> 11, s0 = r0 & 2047;
        bf16x4 v;
#pragma unroll
        for (int rr = 0; rr < 4; ++rr) v[rr] = (bf16_t)(acc[mi][nj][rr] + bb);
        *(bf16x4*)(VT + ((size_t)((b << 3) | h) * 64 + d) * 2048 + s0) = v;
      }
    }
  } else {
    bf16_t* O = (z == 0) ? Qh : Kh;
    const float scl = (z == 0) ? 0.18033688f : 1.0f;  // 0.125 * log2(e)
#pragma unroll
    for (int nj = 0; nj < 4; ++nj) {
      int c = colbase + nj * 16;
      float bb = bias[c];
      int h = c >> 6, d = c & 63;
#pragma unroll
      for (int mi = 0; mi < 4; ++mi)
#pragma unroll
        for (int rr = 0; rr < 4; ++rr) {
          int r = rowbase + mi * 16 + rr;
          int b = r >> 11, s = r & 2047;
          O[((size_t)((b << 3) | h) * 2048 + s) * 64 + d] = (bf16_t)((acc[mi][nj][rr] + bb) * scl);
        }
    }
  }
}

// Output projection: out = ctx @ Wo^T + bo, f32 [8192][512]
__global__ __launch_bounds__(256) void gemm_out_kernel(
    const bf16_t* __restrict__ ctx, const bf16_t* __restrict__ Wo,
    const float* __restrict__ bo, float* __restrict__ out) {
  __shared__ char smem[65536];
  f32x4 acc[4][4] = {};
  gemm_core(ctx, Wo, smem, acc);

  const int lane = threadIdx.x & 63, wid = threadIdx.x >> 6;
  const int wr = wid >> 1, wc = wid & 1;
  const int colbase = blockIdx.x * 128 + wc * 64 + (lane & 15);
  const int rowbase = blockIdx.y * 128 + wr * 64 + ((lane >> 4) << 2);
#pragma unroll
  for (int nj = 0; nj < 4; ++nj) {
    int c = colbase + nj * 16;
    float bb = bo[c];
#pragma unroll
    for (int mi = 0; mi < 4; ++mi)
#pragma unroll
      for (int rr = 0; rr < 4; ++rr) {
        int r = rowbase + mi * 16 + rr;
        out[(size_t)r * 512 + c] = acc[mi][nj][rr] + bb;
      }
  }
}

// ---------------- flash attention, barrier-free ----------------
// grid (32 q-tiles, 32 bh), 256 threads = 4 independent waves, 16 q-rows/wave.
// K read as B-fragments directly from global; V via global V^T; only per-wave
// P tile (2KB) in LDS. Q pre-scaled by 0.125*log2e -> exp2 domain softmax.
__global__ __launch_bounds__(256, 4) void attn_kernel(
    const bf16_t* __restrict__ Qh, const bf16_t* __restrict__ Kh,
    const bf16_t* __restrict__ VT, bf16_t* __restrict__ ctx) {
  __shared__ char smem[8192];
  const int tid = threadIdx.x, lane = tid & 63, wid = tid >> 6;
  char* Pw = smem + wid * 2048;  // [16 q][128B kv], XOR-swizzled
  const int qt = blockIdx.x, bh = blockIdx.y;

  const char* Kbase = (const char*)Kh + (size_t)bh * 262144;  // 2048*128B
  const char* Vbase = (const char*)VT + (size_t)bh * 262144;  // 64*4096B
  const char* Qbase = (const char*)Qh + (size_t)bh * 262144;

  // Q fragment (A-operand): row = lane&15, k = d
  const int qrowA = qt * 64 + wid * 16 + (lane & 15);
  bf16x8 qf[2];
  qf[0] = *(const bf16x8*)(Qbase + (size_t)qrowA * 128 + ((lane >> 4) * 16));
  qf[1] = *(const bf16x8*)(Qbase + (size_t)qrowA * 128 + 64 + ((lane >> 4) * 16));

  f32x4 o_acc[4] = {};
  float m_run[4], l_part[4];
#pragma unroll
  for (int rr = 0; rr < 4; ++rr) { m_run[rr] = -1.0e30f; l_part[rr] = 0.f; }

  // P LDS offsets
  uint32_t pwr[4], pswr[4];
#pragma unroll
  for (int rr = 0; rr < 4; ++rr) {
    uint32_t prow = ((uint32_t)(lane >> 4) << 2) + rr;
    pwr[rr] = prow * 128u;
    pswr[rr] = (prow & 7u) << 4;
  }
  uint32_t prd[2];
#pragma unroll
  for (int kk = 0; kk < 2; ++kk) {
    uint32_t prow = (uint32_t)(lane & 15);
    prd[kk] = prow * 128u + (((uint32_t)kk * 64u + ((lane >> 4) * 16u)) ^ ((prow & 7u) << 4));
  }

#pragma unroll 1
  for (int t = 0; t < 32; ++t) {
    const char* Kt = Kbase + (size_t)t * 8192;
    // K fragments (B-operand): row = kv, k = d — contiguous 16B per lane
    bf16x8 kf[4][2];
#pragma unroll
    for (int nj = 0; nj < 4; ++nj) {
      size_t ro = (size_t)(nj * 16 + (lane & 15)) * 128 + ((lane >> 4) * 16);
      kf[nj][0] = *(const bf16x8*)(Kt + ro);
      kf[nj][1] = *(const bf16x8*)(Kt + ro + 64);
    }
    f32x4 sA[4] = {};
#pragma unroll
    for (int kk = 0; kk < 2; ++kk)
#pragma unroll
      for (int nj = 0; nj < 4; ++nj)
        sA[nj] = __builtin_amdgcn_mfma_f32_16x16x32_bf16(qf[kk], kf[nj][kk], sA[nj], 0, 0, 0);

    // --- online softmax, defer-max (base-2 domain) ---
    float imax[4];
    bool ok = true;
#pragma unroll
    for (int rr = 0; rr < 4; ++rr) {
      float a0 = sA[0][rr], a1 = sA[1][rr], a2 = sA[2][rr], a3 = sA[3][rr];
      float im = fmaxf(fmaxf(a0, a1), fmaxf(a2, a3));
      imax[rr] = im;
      ok = ok && (im <= m_run[rr] + 8.0f);
    }
    if (!__all(ok)) {  // slow path: true row max + rescale (rare: ~tile 0)
#pragma unroll
      for (int rr = 0; rr < 4; ++rr) {
        float mx = imax[rr];
        mx = fmaxf(mx, __shfl_xor(mx, 1));
        mx = fmaxf(mx, __shfl_xor(mx, 2));
        mx = fmaxf(mx, __shfl_xor(mx, 4));
        mx = fmaxf(mx, __shfl_xor(mx, 8));
        float mnew = fmaxf(m_run[rr], mx);
        float sc = __builtin_exp2f(m_run[rr] - mnew);
        m_run[rr] = mnew;
        l_part[rr] *= sc;
#pragma unroll
        for (int dj = 0; dj < 4; ++dj) o_acc[dj][rr] *= sc;
      }
    }
    // ensure prior iteration's P reads are complete before overwriting
    asm volatile("s_waitcnt lgkmcnt(0)" ::: "memory");
    __builtin_amdgcn_sched_barrier(0);
#pragma unroll
    for (int rr = 0; rr < 4; ++rr) {
      float m = m_run[rr];
      float p0 = __builtin_exp2f(sA[0][rr] - m);
      float p1 = __builtin_exp2f(sA[1][rr] - m);
      float p2 = __builtin_exp2f(sA[2][rr] - m);
      float p3 = __builtin_exp2f(sA[3][rr] - m);
      l_part[rr] += (p0 + p1) + (p2 + p3);
      char* pr = Pw + pwr[rr];
      uint32_t sw = pswr[rr];
      uint32_t cb = (uint32_t)(lane & 15) * 2u;
      *(bf16_t*)(pr + ((cb)       ^ sw)) = (bf16_t)p0;
      *(bf16_t*)(pr + ((cb + 32u) ^ sw)) = (bf16_t)p1;
      *(bf16_t*)(pr + ((cb + 64u) ^ sw)) = (bf16_t)p2;
      *(bf16_t*)(pr + ((cb + 96u) ^ sw)) = (bf16_t)p3;
    }
    asm volatile("s_waitcnt lgkmcnt(0)" ::: "memory");
    __builtin_amdgcn_sched_barrier(0);

    // --- O += P V  (A = P from LDS, B = V^T rows from global) ---
    bf16x8 pf[2];
    pf[0] = *(const bf16x8*)(Pw + prd[0]);
    pf[1] = *(const bf16x8*)(Pw + prd[1]);
    bf16x8 vf[4][2];
#pragma unroll
    for (int dj = 0; dj < 4; ++dj) {
      size_t vo = ((size_t)(dj * 16 + (lane & 15)) * 2048 + (size_t)t * 64 + ((lane >> 4) * 8)) * 2;
      vf[dj][0] = *(const bf16x8*)(Vbase + vo);
      vf[dj][1] = *(const bf16x8*)(Vbase + vo + 64);
    }
#pragma unroll
    for (int kk = 0; kk < 2; ++kk)
#pragma unroll
      for (int dj = 0; dj < 4; ++dj)
        o_acc[dj] = __builtin_amdgcn_mfma_f32_16x16x32_bf16(pf[kk], vf[dj][kk], o_acc[dj], 0, 0, 0);
    __builtin_amdgcn_sched_barrier(0);
  }

  // epilogue: reduce l across the 16-lane row group, normalize, write ctx
  const int b = bh >> 3, h = bh & 7;
#pragma unroll
  for (int rr = 0; rr < 4; ++rr) {
    float l = l_part[rr];
    l += __shfl_xor(l, 1);
    l += __shfl_xor(l, 2);
    l += __shfl_xor(l, 4);
    l += __shfl_xor(l, 8);
    float inv = 1.0f / l;
    int qrow = qt * 64 + wid * 16 + ((lane >> 4) << 2) + rr;
    size_t base = ((size_t)(b * 2048 + qrow)) * 512 + h * 64 + (lane & 15);
#pragma unroll
    for (int dj = 0; dj < 4; ++dj)
      ctx[base + dj * 16] = (bf16_t)(o_acc[dj][rr] * inv);
  }
}

extern "C" void kernel_launch(void* const* d_in, const int* in_sizes, int n_in,
                              void* d_out, int out_size, void* d_ws, size_t ws_size,
                              hipStream_t stream) {
  const float* x  = (const float*)d_in[0];
  const float* q  = (const float*)d_in[1];
  const float* Wq = (const float*)d_in[2];
  const float* bq = (const float*)d_in[3];
  const float* Wk = (const float*)d_in[4];
  const float* bk = (const float*)d_in[5];
  const float* Wv = (const float*)d_in[6];
  const float* bv = (const float*)d_in[7];
  const float* Wo = (const float*)d_in[8];
  const float* bo = (const float*)d_in[9];

  char* ws = (char*)d_ws;
  bf16_t* xb  = (bf16_t*)(ws + 0);          // 8 MB
  bf16_t* qb  = (bf16_t*)(ws + 8388608);    // 8 MB
  bf16_t* Wb  = (bf16_t*)(ws + 16777216);   // 4 x 512KB
  bf16_t* Qh  = (bf16_t*)(ws + 18874368);   // 8 MB [32][2048][64]
  bf16_t* Kh  = (bf16_t*)(ws + 27262976);   // 8 MB [32][2048][64]
  bf16_t* VT  = (bf16_t*)(ws + 35651584);   // 8 MB [32][64][2048]
  bf16_t* ctx = (bf16_t*)(ws + 44040192);   // 8 MB

  cvt2_kernel<<<dim3(2048, 2), 256, 0, stream>>>(x, q, xb, qb);
  cvtw_kernel<<<dim3(128, 4), 256, 0, stream>>>(Wq, Wk, Wv, Wo, Wb);
  gemm_qkv_kernel<<<dim3(4, 64, 3), 256, 0, stream>>>(xb, qb, Wb, bq, bk, bv, Qh, Kh, VT);
  attn_kernel<<<dim3(32, 32), 256, 0, stream>>>(Qh, Kh, VT, ctx);
  gemm_out_kernel<<<dim3(4, 64), 256, 0, stream>>>(ctx, Wb + 3 * 262144, bo, (float*)d_out);
}

// Round 3
// 128.103 us; speedup vs baseline: 2.1788x; 2.1788x over previous
//
#include <hip/hip_runtime.h>
#include <stdint.h>

typedef __bf16 bf16_t;
typedef bf16_t bf16x8 __attribute__((ext_vector_type(8)));
typedef bf16_t bf16x4 __attribute__((ext_vector_type(4)));
typedef float f32x4 __attribute__((ext_vector_type(4)));

#define DEV __device__ __forceinline__

DEV void gload_lds16(const void* g, void* l) {
  __builtin_amdgcn_global_load_lds(
      (__attribute__((address_space(1))) void*)(g),
      (__attribute__((address_space(3))) void*)(l), 16, 0, 0);
}

// ---------------- convert kernels ----------------
__global__ __launch_bounds__(256) void cvt2_kernel(
    const float* __restrict__ x, const float* __restrict__ q,
    bf16_t* __restrict__ xb, bf16_t* __restrict__ qb) {
  const float* s = blockIdx.y ? q : x;
  bf16_t* d = blockIdx.y ? qb : xb;
  int i = blockIdx.x * 256 + threadIdx.x;
  if (i < 524288) {
    const float4* sp = (const float4*)s + (size_t)i * 2;
    float4 a = sp[0], b = sp[1];
    bf16x8 o;
    o[0] = (bf16_t)a.x; o[1] = (bf16_t)a.y; o[2] = (bf16_t)a.z; o[3] = (bf16_t)a.w;
    o[4] = (bf16_t)b.x; o[5] = (bf16_t)b.y; o[6] = (bf16_t)b.z; o[7] = (bf16_t)b.w;
    *(bf16x8*)(d + (size_t)i * 8) = o;
  }
}

__global__ __launch_bounds__(256) void cvtw_kernel(
    const float* __restrict__ Wq, const float* __restrict__ Wk,
    const float* __restrict__ Wv, const float* __restrict__ Wo,
    bf16_t* __restrict__ dst) {
  int y = blockIdx.y;
  const float* s = (y == 0) ? Wq : (y == 1) ? Wk : (y == 2) ? Wv : Wo;
  bf16_t* d = dst + (size_t)y * 262144;
  int i = blockIdx.x * 256 + threadIdx.x;
  if (i < 32768) {
    const float4* sp = (const float4*)s + (size_t)i * 2;
    float4 a = sp[0], b = sp[1];
    bf16x8 o;
    o[0] = (bf16_t)a.x; o[1] = (bf16_t)a.y; o[2] = (bf16_t)a.z; o[3] = (bf16_t)a.w;
    o[4] = (bf16_t)b.x; o[5] = (bf16_t)b.y; o[6] = (bf16_t)b.z; o[7] = (bf16_t)b.w;
    *(bf16x8*)(d + (size_t)i * 8) = o;
  }
}

// ---------------- GEMM core: C[128x128] = A[128xK] * W[128xK]^T ----------------
DEV void gemm_core(const bf16_t* __restrict__ A, const bf16_t* __restrict__ W,
                   char* smem, f32x4 (&acc)[4][4]) {
  const int tid = threadIdx.x;
  const int lane = tid & 63;
  const int wid = tid >> 6;
  const int wr = wid >> 1, wc = wid & 1;
  const int bx = blockIdx.x, by = blockIdx.y;

  uint32_t goffA[4], goffB[4], ldsoff[4];
#pragma unroll
  for (int c = 0; c < 4; ++c) {
    uint32_t o = (uint32_t)wid * 4096u + (uint32_t)c * 1024u + (uint32_t)lane * 16u;
    uint32_t row = o >> 7;
    uint32_t inner = (o & 127u) ^ ((row & 7u) << 4);
    goffA[c] = ((uint32_t)by * 128u + row) * 1024u + inner;
    goffB[c] = ((uint32_t)bx * 128u + row) * 1024u + inner;
    ldsoff[c] = o - (uint32_t)lane * 16u;
  }
  uint32_t offA[4][2], offB[4][2];
#pragma unroll
  for (int i = 0; i < 4; ++i)
#pragma unroll
    for (int kk = 0; kk < 2; ++kk) {
      uint32_t ra = (uint32_t)(wr * 64 + i * 16 + (lane & 15));
      offA[i][kk] = ra * 128u + (((uint32_t)kk * 64u + ((lane >> 4) * 16u)) ^ ((ra & 7u) << 4));
      uint32_t rb = (uint32_t)(wc * 64 + i * 16 + (lane & 15));
      offB[i][kk] = rb * 128u + (((uint32_t)kk * 64u + ((lane >> 4) * 16u)) ^ ((rb & 7u) << 4));
    }

  const char* Ab = (const char*)A;
  const char* Wb = (const char*)W;

#pragma unroll
  for (int c = 0; c < 4; ++c) {
    gload_lds16(Ab + goffA[c], smem + ldsoff[c]);
    gload_lds16(Wb + goffB[c], smem + 16384 + ldsoff[c]);
  }
  asm volatile("s_waitcnt vmcnt(0)" ::: "memory");
  __syncthreads();

#pragma unroll 1
  for (int kt = 0; kt < 8; ++kt) {
    const int buf = kt & 1;
    char* cur = smem + buf * 32768;
    if (kt < 7) {
      char* nxt = smem + (buf ^ 1) * 32768;
      uint32_t gk = (uint32_t)(kt + 1) * 128u;
#pragma unroll
      for (int c = 0; c < 4; ++c) {
        gload_lds16(Ab + goffA[c] + gk, nxt + ldsoff[c]);
        gload_lds16(Wb + goffB[c] + gk, nxt + 16384 + ldsoff[c]);
      }
    }
    bf16x8 af[4][2], bfr[4][2];
#pragma unroll
    for (int kk = 0; kk < 2; ++kk)
#pragma unroll
      for (int i = 0; i < 4; ++i) {
        af[i][kk] = *(const bf16x8*)(cur + offA[i][kk]);
        bfr[i][kk] = *(const bf16x8*)(cur + 16384 + offB[i][kk]);
      }
#pragma unroll
    for (int kk = 0; kk < 2; ++kk)
#pragma unroll
      for (int mi = 0; mi < 4; ++mi)
#pragma unroll
        for (int nj = 0; nj < 4; ++nj)
          acc[mi][nj] = __builtin_amdgcn_mfma_f32_16x16x32_bf16(
              af[mi][kk], bfr[nj][kk], acc[mi][nj], 0, 0, 0);
    asm volatile("s_waitcnt vmcnt(0)" ::: "memory");
    __syncthreads();
  }
}

// QKV projection. z=0 -> Q (pre-scaled by 0.125*log2e), z=1 -> K, z=2 -> V^T.
// Q,K layout [B*H][S][64]; V stored transposed [B*H][64][S].
__global__ __launch_bounds__(256) void gemm_qkv_kernel(
    const bf16_t* __restrict__ xb, const bf16_t* __restrict__ qb,
    const bf16_t* __restrict__ Wb, const float* __restrict__ bq,
    const float* __restrict__ bk, const float* __restrict__ bv,
    bf16_t* __restrict__ Qh, bf16_t* __restrict__ Kh, bf16_t* __restrict__ VT) {
  __shared__ char smem[65536];
  const int z = blockIdx.z;
  const bf16_t* A = (z == 0) ? qb : xb;
  const bf16_t* W = Wb + (size_t)z * 262144;
  const float* bias = (z == 0) ? bq : (z == 1) ? bk : bv;

  f32x4 acc[4][4] = {};
  gemm_core(A, W, smem, acc);

  const int lane = threadIdx.x & 63, wid = threadIdx.x >> 6;
  const int wr = wid >> 1, wc = wid & 1;
  const int colbase = blockIdx.x * 128 + wc * 64 + (lane & 15);
  const int rowbase = blockIdx.y * 128 + wr * 64 + ((lane >> 4) << 2);

  if (z == 2) {
    // V^T: VT[(bh*64 + d)*2048 + s], rr index is s-contiguous -> 8B stores
#pragma unroll
    for (int nj = 0; nj < 4; ++nj) {
      int c = colbase + nj * 16;
      float bb = bias[c];
      int h = c >> 6, d = c & 63;
#pragma unroll
      for (int mi = 0; mi < 4; ++mi) {
        int r0 = rowbase + mi * 16;
        int b = r0 >> 11, s0 = r0 & 2047;
        bf16x4 v;
#pragma unroll
        for (int rr = 0; rr < 4; ++rr) v[rr] = (bf16_t)(acc[mi][nj][rr] + bb);
        *(bf16x4*)(VT + ((size_t)((b << 3) | h) * 64 + d) * 2048 + s0) = v;
      }
    }
  } else {
    bf16_t* O = (z == 0) ? Qh : Kh;
    const float scl = (z == 0) ? 0.18033688f : 1.0f;  // 0.125 * log2(e)
#pragma unroll
    for (int nj = 0; nj < 4; ++nj) {
      int c = colbase + nj * 16;
      float bb = bias[c];
      int h = c >> 6, d = c & 63;
#pragma unroll
      for (int mi = 0; mi < 4; ++mi)
#pragma unroll
        for (int rr = 0; rr < 4; ++rr) {
          int r = rowbase + mi * 16 + rr;
          int b = r >> 11, s = r & 2047;
          O[((size_t)((b << 3) | h) * 2048 + s) * 64 + d] = (bf16_t)((acc[mi][nj][rr] + bb) * scl);
        }
    }
  }
}

// Output projection: out = ctx @ Wo^T + bo, f32 [8192][512]
__global__ __launch_bounds__(256) void gemm_out_kernel(
    const bf16_t* __restrict__ ctx, const bf16_t* __restrict__ Wo,
    const float* __restrict__ bo, float* __restrict__ out) {
  __shared__ char smem[65536];
  f32x4 acc[4][4] = {};
  gemm_core(ctx, Wo, smem, acc);

  const int lane = threadIdx.x & 63, wid = threadIdx.x >> 6;
  const int wr = wid >> 1, wc = wid & 1;
  const int colbase = blockIdx.x * 128 + wc * 64 + (lane & 15);
  const int rowbase = blockIdx.y * 128 + wr * 64 + ((lane >> 4) << 2);
#pragma unroll
  for (int nj = 0; nj < 4; ++nj) {
    int c = colbase + nj * 16;
    float bb = bo[c];
#pragma unroll
    for (int mi = 0; mi < 4; ++mi)
#pragma unroll
      for (int rr = 0; rr < 4; ++rr) {
        int r = rowbase + mi * 16 + rr;
        out[(size_t)r * 512 + c] = acc[mi][nj][rr] + bb;
      }
  }
}

// ---------------- flash attention, double-buffered LDS staging ----------------
// grid (16 q-tiles, 32 bh), 4 waves x 32 q-rows. KVBLK=64, 32 iterations.
// K and V^T tiles staged via global_load_lds (pre-swizzled source), prefetched
// one tile ahead (T3-minimum 2-phase). Q pre-scaled -> exp2-domain softmax
// with defer-max; l reduced once in epilogue.
__global__ __launch_bounds__(256, 2) void attn_kernel(
    const bf16_t* __restrict__ Qh, const bf16_t* __restrict__ Kh,
    const bf16_t* __restrict__ VT, bf16_t* __restrict__ ctx) {
  __shared__ char smem[49152];
  char* Kb = smem;            // 2 x 8KB: K tile [64 kv][128B d], swizzled
  char* Vb = smem + 16384;    // 2 x 8KB: V^T tile [64 d][128B kv], swizzled
  const int tid = threadIdx.x, lane = tid & 63, wid = tid >> 6;
  char* Pw = smem + 32768 + wid * 4096;  // per-wave P [32 q][128B kv], swizzled
  const int qt = blockIdx.x, bh = blockIdx.y;

  const char* Kbase = (const char*)Kh + (size_t)bh * 262144;  // [2048][128B]
  const char* Vbase = (const char*)VT + (size_t)bh * 262144;  // [64][4096B]
  const char* Qbase = (const char*)Qh + (size_t)bh * 262144;

  // Q fragments in registers
  bf16x8 qf[2][2];
#pragma unroll
  for (int mi = 0; mi < 2; ++mi)
#pragma unroll
    for (int kk = 0; kk < 2; ++kk) {
      int qrow = qt * 128 + wid * 32 + mi * 16 + (lane & 15);
      qf[mi][kk] = *(const bf16x8*)(Qbase + (size_t)qrow * 128 + kk * 64 + ((lane >> 4) * 16));
    }

  // staging offsets (2 issues each for K and V per tile)
  uint32_t kgo[2], vgo[2], lo[2];
#pragma unroll
  for (int c = 0; c < 2; ++c) {
    uint32_t o = (uint32_t)c * 4096u + (uint32_t)wid * 1024u + (uint32_t)lane * 16u;
    uint32_t row = o >> 7;
    uint32_t inner = (o & 127u) ^ ((row & 7u) << 4);
    kgo[c] = row * 128u + inner;   // + t*8192 (K row stride 128B)
    vgo[c] = row * 4096u + inner;  // + t*128  (VT row stride 4096B)
    lo[c] = o - (uint32_t)lane * 16u;  // wave-uniform LDS base
  }

  // fragment read offsets (shared by K and V tiles)
  uint32_t fro[4][2];
#pragma unroll
  for (int nj = 0; nj < 4; ++nj)
#pragma unroll
    for (int kk = 0; kk < 2; ++kk) {
      uint32_t row = (uint32_t)(nj * 16 + (lane & 15));
      fro[nj][kk] = row * 128u + (((uint32_t)kk * 64u + ((lane >> 4) * 16u)) ^ ((row & 7u) << 4));
    }

  // P offsets
  uint32_t pwr[2][4], psw[2][4];
#pragma unroll
  for (int mi = 0; mi < 2; ++mi)
#pragma unroll
    for (int rr = 0; rr < 4; ++rr) {
      uint32_t prow = (uint32_t)(mi * 16 + ((lane >> 4) << 2) + rr);
      pwr[mi][rr] = prow * 128u;
      psw[mi][rr] = (prow & 7u) << 4;
    }
  uint32_t prd[2][2];
#pragma unroll
  for (int mi = 0; mi < 2; ++mi)
#pragma unroll
    for (int kk = 0; kk < 2; ++kk) {
      uint32_t prow = (uint32_t)(mi * 16 + (lane & 15));
      prd[mi][kk] = prow * 128u + (((uint32_t)kk * 64u + ((lane >> 4) * 16u)) ^ ((prow & 7u) << 4));
    }

  f32x4 o_acc[2][4] = {};
  float m_run[2][4], l_part[2][4];
#pragma unroll
  for (int mi = 0; mi < 2; ++mi)
#pragma unroll
    for (int rr = 0; rr < 4; ++rr) { m_run[mi][rr] = -1.0e30f; l_part[mi][rr] = 0.f; }

  // prologue: stage tile 0 into buf 0
#pragma unroll
  for (int c = 0; c < 2; ++c) {
    gload_lds16(Kbase + kgo[c], Kb + lo[c]);
    gload_lds16(Vbase + vgo[c], Vb + lo[c]);
  }
  asm volatile("s_waitcnt vmcnt(0)" ::: "memory");
  __syncthreads();

#pragma unroll 1
  for (int t = 0; t < 32; ++t) {
    const uint32_t cur = ((uint32_t)t & 1u) << 13;
    // prefetch next tile into the other buffer (stays in flight during compute)
    if (t < 31) {
      const uint32_t nxt = cur ^ 8192u;
      const char* Kn = Kbase + (size_t)(t + 1) * 8192;
      const char* Vn = Vbase + (size_t)(t + 1) * 128;
#pragma unroll
      for (int c = 0; c < 2; ++c) {
        gload_lds16(Kn + kgo[c], Kb + nxt + lo[c]);
        gload_lds16(Vn + vgo[c], Vb + nxt + lo[c]);
      }
    }

    // S = Q K^T
    f32x4 sA[2][4] = {};
#pragma unroll
    for (int kk = 0; kk < 2; ++kk) {
      bf16x8 kf[4];
#pragma unroll
      for (int nj = 0; nj < 4; ++nj)
        kf[nj] = *(const bf16x8*)(Kb + cur + fro[nj][kk]);
#pragma unroll
      for (int mi = 0; mi < 2; ++mi)
#pragma unroll
        for (int nj = 0; nj < 4; ++nj)
          sA[mi][nj] = __builtin_amdgcn_mfma_f32_16x16x32_bf16(qf[mi][kk], kf[nj], sA[mi][nj], 0, 0, 0);
    }

    // online softmax, defer-max, base-2 domain
    float imax[2][4];
    bool ok = true;
#pragma unroll
    for (int mi = 0; mi < 2; ++mi)
#pragma unroll
      for (int rr = 0; rr < 4; ++rr) {
        float a0 = sA[mi][0][rr], a1 = sA[mi][1][rr], a2 = sA[mi][2][rr], a3 = sA[mi][3][rr];
        float im = fmaxf(fmaxf(a0, a1), fmaxf(a2, a3));
        imax[mi][rr] = im;
        ok = ok && (im <= m_run[mi][rr] + 8.0f);
      }
    if (!__all(ok)) {  // slow path (rare: ~tile 0): true row max + rescale
#pragma unroll
      for (int mi = 0; mi < 2; ++mi)
#pragma unroll
        for (int rr = 0; rr < 4; ++rr) {
          float mx = imax[mi][rr];
          mx = fmaxf(mx, __shfl_xor(mx, 1));
          mx = fmaxf(mx, __shfl_xor(mx, 2));
          mx = fmaxf(mx, __shfl_xor(mx, 4));
          mx = fmaxf(mx, __shfl_xor(mx, 8));
          float mnew = fmaxf(m_run[mi][rr], mx);
          float sc = __builtin_exp2f(m_run[mi][rr] - mnew);
          m_run[mi][rr] = mnew;
          l_part[mi][rr] *= sc;
#pragma unroll
          for (int dj = 0; dj < 4; ++dj) o_acc[mi][dj][rr] *= sc;
        }
    }

    // P = exp2(S - m) -> bf16 -> per-wave LDS (prev iter's P reads already
    // drained by the end-of-iteration barrier)
#pragma unroll
    for (int mi = 0; mi < 2; ++mi)
#pragma unroll
      for (int rr = 0; rr < 4; ++rr) {
        float m = m_run[mi][rr];
        float p0 = __builtin_exp2f(sA[mi][0][rr] - m);
        float p1 = __builtin_exp2f(sA[mi][1][rr] - m);
        float p2 = __builtin_exp2f(sA[mi][2][rr] - m);
        float p3 = __builtin_exp2f(sA[mi][3][rr] - m);
        l_part[mi][rr] += (p0 + p1) + (p2 + p3);
        char* pr = Pw + pwr[mi][rr];
        uint32_t sw = psw[mi][rr];
        uint32_t cb = (uint32_t)(lane & 15) * 2u;
        *(bf16_t*)(pr + ((cb)       ^ sw)) = (bf16_t)p0;
        *(bf16_t*)(pr + ((cb + 32u) ^ sw)) = (bf16_t)p1;
        *(bf16_t*)(pr + ((cb + 64u) ^ sw)) = (bf16_t)p2;
        *(bf16_t*)(pr + ((cb + 96u) ^ sw)) = (bf16_t)p3;
      }
    // cross-lane P handoff within the wave
    asm volatile("s_waitcnt lgkmcnt(0)" ::: "memory");
    __builtin_amdgcn_sched_barrier(0);

    // O += P V  (A = P from LDS, B = V^T rows from LDS)
#pragma unroll
    for (int kk = 0; kk < 2; ++kk) {
      bf16x8 pf[2], vf[4];
#pragma unroll
      for (int mi = 0; mi < 2; ++mi)
        pf[mi] = *(const bf16x8*)(Pw + prd[mi][kk]);
#pragma unroll
      for (int dj = 0; dj < 4; ++dj)
        vf[dj] = *(const bf16x8*)(Vb + cur + fro[dj][kk]);
#pragma unroll
      for (int mi = 0; mi < 2; ++mi)
#pragma unroll
        for (int dj = 0; dj < 4; ++dj)
          o_acc[mi][dj] = __builtin_amdgcn_mfma_f32_16x16x32_bf16(pf[mi], vf[dj][0] == vf[dj][0] ? vf[dj] : vf[dj], o_acc[mi][dj], 0, 0, 0);
    }

    // single drain per iteration: prefetch had the whole compute phase to land
    asm volatile("s_waitcnt vmcnt(0)" ::: "memory");
    __syncthreads();
  }

  // epilogue: reduce l across the 16-lane row group, normalize, write ctx
  const int b = bh >> 3, h = bh & 7;
#pragma unroll
  for (int mi = 0; mi < 2; ++mi)
#pragma unroll
    for (int rr = 0; rr < 4; ++rr) {
      float l = l_part[mi][rr];
      l += __shfl_xor(l, 1);
      l += __shfl_xor(l, 2);
      l += __shfl_xor(l, 4);
      l += __shfl_xor(l, 8);
      float inv = 1.0f / l;
      int qrow = qt * 128 + wid * 32 + mi * 16 + ((lane >> 4) << 2) + rr;
      size_t base = ((size_t)(b * 2048 + qrow)) * 512 + h * 64 + (lane & 15);
#pragma unroll
      for (int dj = 0; dj < 4; ++dj)
        ctx[base + dj * 16] = (bf16_t)(o_acc[mi][dj][rr] * inv);
    }
}

extern "C" void kernel_launch(void* const* d_in, const int* in_sizes, int n_in,
                              void* d_out, int out_size, void* d_ws, size_t ws_size,
                              hipStream_t stream) {
  const float* x  = (const float*)d_in[0];
  const float* q  = (const float*)d_in[1];
  const float* Wq = (const float*)d_in[2];
  const float* bq = (const float*)d_in[3];
  const float* Wk = (const float*)d_in[4];
  const float* bk = (const float*)d_in[5];
  const float* Wv = (const float*)d_in[6];
  const float* bv = (const float*)d_in[7];
  const float* Wo = (const float*)d_in[8];
  const float* bo = (const float*)d_in[9];

  char* ws = (char*)d_ws;
  bf16_t* xb  = (bf16_t*)(ws + 0);          // 8 MB
  bf16_t* qb  = (bf16_t*)(ws + 8388608);    // 8 MB
  bf16_t* Wb  = (bf16_t*)(ws + 16777216);   // 4 x 512KB
  bf16_t* Qh  = (bf16_t*)(ws + 18874368);   // 8 MB [32][2048][64]
  bf16_t* Kh  = (bf16_t*)(ws + 27262976);   // 8 MB [32][2048][64]
  bf16_t* VT  = (bf16_t*)(ws + 35651584);   // 8 MB [32][64][2048]
  bf16_t* ctx = (bf16_t*)(ws + 44040192);   // 8 MB

  cvt2_kernel<<<dim3(2048, 2), 256, 0, stream>>>(x, q, xb, qb);
  cvtw_kernel<<<dim3(128, 4), 256, 0, stream>>>(Wq, Wk, Wv, Wo, Wb);
  gemm_qkv_kernel<<<dim3(4, 64, 3), 256, 0, stream>>>(xb, qb, Wb, bq, bk, bv, Qh, Kh, VT);
  attn_kernel<<<dim3(16, 32), 256, 0, stream>>>(Qh, Kh, VT, ctx);
  gemm_out_kernel<<<dim3(4, 64), 256, 0, stream>>>(ctx, Wb + 3 * 262144, bo, (float*)d_out);
}